// Round 1
// baseline (191.335 us; speedup 1.0000x reference)
//
#include <hip/hip_runtime.h>

// TemporalCorrelation: out[b,o,t] = <f1n[b,:,t], f2n[b,:,clamp(t+o-10)]>
// B=8, C=1024, T=4096, 21 offsets. Normalization folded into a final divide.

constexpr int B  = 8;
constexpr int C  = 1024;
constexpr int T  = 4096;
constexpr int NO = 21;        // 2*MAX_DISP+1
constexpr int MD = 10;        // MAX_DISP
constexpr int TT = 512;       // output columns per block
constexpr int CC = 8;         // staged channel rows per chunk
constexpr int WROW = 536;     // staged floats per row: [t0-12, t0+524)
constexpr int F4R  = WROW / 4;        // 134 float4 per row
constexpr int CHUNK_F4 = CC * F4R;    // 1072 float4 per chunk

// ---------------------------------------------------------------------------
// Kernel 1: raw sliding dots + sum-of-squares partials, one C-slice per block.
// Each thread owns 2 adjacent columns (t0+2p, t0+2p+1); 21 offsets each.
// f2 window double-buffered in LDS; f1 read direct (coalesced float2).
// ---------------------------------------------------------------------------
__global__ __launch_bounds__(256)
void corr_main(const float* __restrict__ f1, const float* __restrict__ f2,
               float* __restrict__ dots, float* __restrict__ s1p,
               float* __restrict__ s2p, int CS)
{
    __shared__ float4 smf4[2 * CHUNK_F4];   // 34 KB

    const int tile = blockIdx.x;
    const int b    = blockIdx.y;
    const int cs   = blockIdx.z;
    const int t0   = tile * TT;
    const int nc   = C / CS;                // channels this block
    const int c0   = cs * nc;
    const int NCH  = nc / CC;               // chunks
    const int tid  = (int)threadIdx.x;
    const int p    = tid;                   // column-pair id, cols 2p, 2p+1

    // --- staging map (constant across chunks) ---
    int  rowm[5], tsrcm[5];
    bool act[5];
#pragma unroll
    for (int m = 0; m < 5; ++m) {
        int idx  = m * 256 + tid;
        act[m]   = idx < CHUNK_F4;
        int r    = idx / F4R;
        int c4   = idx - r * F4R;
        rowm[m]  = r;
        int t    = t0 - 12 + 4 * c4;        // 16B-aligned source start
        tsrcm[m] = min(max(t, 0), T - 4);   // clamp for safety; garbage halo
    }                                        // entries are redirected later

    const size_t bc0    = (size_t)(b * C + c0);
    const float* f1base = f1 + bc0 * T + t0 + 2 * p;
    const float* f2base = f2 + bc0 * T;

    float accA[NO], accB[NO];
#pragma unroll
    for (int o = 0; o < NO; ++o) { accA[o] = 0.f; accB[o] = 0.f; }
    float s1a = 0.f, s1b = 0.f, s2a = 0.f, s2b = 0.f;

    // prologue: load chunk 0 into regs
    float4 sreg[5];
#pragma unroll
    for (int m = 0; m < 5; ++m)
        if (act[m])
            sreg[m] = *(const float4*)(f2base + (size_t)rowm[m] * T + tsrcm[m]);

    const float2* smr = (const float2*)smf4;

    for (int k = 0; k < NCH; ++k) {
        const int buf = k & 1;
        // commit staged regs to LDS
#pragma unroll
        for (int m = 0; m < 5; ++m)
            if (act[m]) smf4[buf * CHUNK_F4 + m * 256 + tid] = sreg[m];
        __syncthreads();

        // prefetch next chunk into regs (hides HBM latency under compute)
        if (k + 1 < NCH) {
            const float* nb = f2base + (size_t)(k + 1) * CC * T;
#pragma unroll
            for (int m = 0; m < 5; ++m)
                if (act[m])
                    sreg[m] = *(const float4*)(nb + (size_t)rowm[m] * T + tsrcm[m]);
        }

        // f1 values for this chunk (coalesced float2 per row)
        float2 f1v[CC];
        const float* fb = f1base + (size_t)k * CC * T;
#pragma unroll
        for (int kc = 0; kc < CC; ++kc)
            f1v[kc] = *(const float2*)(fb + (size_t)kc * T);

        const int base2 = buf * (CHUNK_F4 * 2) + (p + 1);  // float2 units
#pragma unroll
        for (int kc = 0; kc < CC; ++kc) {
            // window floats [2p+2 .. 2p+23] -> w[0..21]; ds_read_b64, even
            // lane-dense addresses => conflict-free
            float w[NO + 1];
#pragma unroll
            for (int j = 0; j < 11; ++j) {
                float2 v = smr[base2 + kc * (WROW / 2) + j];
                w[2 * j] = v.x; w[2 * j + 1] = v.y;
            }
            float2 a = f1v[kc];
            s1a += a.x * a.x; s1b += a.y * a.y;
            s2a += w[10] * w[10]; s2b += w[11] * w[11];  // own f2 columns
#pragma unroll
            for (int o = 0; o < NO; ++o) {
                accA[o] += a.x * w[o];       // col 2p,   offset o
                accB[o] += a.y * w[o + 1];   // col 2p+1, offset o
            }
        }
    }

    // write partials
    const size_t tcol = (size_t)t0 + 2 * p;
#pragma unroll
    for (int o = 0; o < NO; ++o) {
        float2 v; v.x = accA[o]; v.y = accB[o];
        *(float2*)(dots + (((size_t)(cs * B + b) * NO + o) * T + tcol)) = v;
    }
    {
        float2 v;
        v.x = s1a; v.y = s1b;
        *(float2*)(s1p + (size_t)(cs * B + b) * T + tcol) = v;
        v.x = s2a; v.y = s2b;
        *(float2*)(s2p + (size_t)(cs * B + b) * T + tcol) = v;
    }
}

// ---------------------------------------------------------------------------
// Kernel 2a: reduce CS partial sums-of-squares -> 1/max(norm, eps) tables
// ---------------------------------------------------------------------------
__global__ void corr_norm(const float* __restrict__ s1p,
                          const float* __restrict__ s2p,
                          float* __restrict__ inv1, float* __restrict__ inv2,
                          int CS)
{
    int i = blockIdx.x * 256 + (int)threadIdx.x;   // i = b*T + t
    if (i >= B * T) return;
    float a = 0.f, c = 0.f;
    for (int cs = 0; cs < CS; ++cs) {
        a += s1p[(size_t)cs * B * T + i];
        c += s2p[(size_t)cs * B * T + i];
    }
    inv1[i] = 1.f / fmaxf(sqrtf(a), 1e-12f);
    inv2[i] = 1.f / fmaxf(sqrtf(c), 1e-12f);
}

// ---------------------------------------------------------------------------
// Kernel 2b: sum CS dot partials, redirect clamped offsets (replicate-pad
// duplicates an in-range entry of the same column), normalize, write out.
// One thread per (b,t) column => in-place safe even when dots aliases out.
// ---------------------------------------------------------------------------
__global__ void corr_finalize(const float* __restrict__ dots,
                              const float* __restrict__ inv1,
                              const float* __restrict__ inv2,
                              float* __restrict__ out, int CS)
{
    int i = blockIdx.x * 256 + (int)threadIdx.x;
    if (i >= B * T) return;
    const int b = i >> 12;          // /T
    const int t = i & (T - 1);
    const float i1 = inv1[i];

    float d[NO];
#pragma unroll
    for (int o = 0; o < NO; ++o) {
        int tp = t + o - MD;
        tp = min(max(tp, 0), T - 1);
        const int o2 = tp - t + MD;          // redirected (valid) offset
        float s = 0.f;
        for (int cs = 0; cs < CS; ++cs)
            s += dots[(((size_t)cs * B + b) * NO + o2) * T + t];
        d[o] = s * i1 * inv2[b * T + tp];
    }
#pragma unroll
    for (int o = 0; o < NO; ++o)
        out[((size_t)b * NO + o) * T + t] = d[o];
}

// ---------------------------------------------------------------------------
extern "C" void kernel_launch(void* const* d_in, const int* in_sizes, int n_in,
                              void* d_out, int out_size, void* d_ws, size_t ws_size,
                              hipStream_t stream)
{
    const float* f1 = (const float*)d_in[0];
    const float* f2 = (const float*)d_in[1];
    float* out = (float*)d_out;

    const size_t BT = (size_t)B * T;
    auto need = [](int cs) {
        return sizeof(float) * ((size_t)cs * B * NO * T + 2 * (size_t)cs * B * T
                                + 2 * (size_t)B * T);
    };
    int CS = 1;
    if      (ws_size >= need(8)) CS = 8;
    else if (ws_size >= need(4)) CS = 4;
    else if (ws_size >= need(2)) CS = 2;

    float* wsf = (float*)d_ws;
    float *dots, *s1p;
    if (CS == 1 && ws_size < need(1)) {
        dots = out;          // CS=1: full dots fit exactly in d_out
        s1p  = wsf;
    } else {
        dots = wsf;
        s1p  = dots + (size_t)CS * B * NO * T;
    }
    float* s2p  = s1p + (size_t)CS * BT;
    float* inv1 = s2p + (size_t)CS * BT;
    float* inv2 = inv1 + BT;

    dim3 g1(T / TT, B, CS);
    corr_main<<<g1, dim3(256), 0, stream>>>(f1, f2, dots, s1p, s2p, CS);

    const int nbt = (B * T) / 256;   // 128 blocks
    corr_norm<<<nbt, 256, 0, stream>>>(s1p, s2p, inv1, inv2, CS);
    corr_finalize<<<nbt, 256, 0, stream>>>(dots, inv1, inv2, out, CS);
}

// Round 2
// 72.364 us; speedup vs baseline: 2.6440x; 2.6440x over previous
//
#include <hip/hip_runtime.h>

// TemporalCorrelation, fully fused single kernel.
// out[b,o,t] = <f1[b,:,t], f2[b,:,clamp(t+o-10)]> / (||f1[:,t]||*||f2[:,t']||)
// Block: 1024 threads = 32 col-pairs (p) x 32 channel-groups (g).
// Tile: 64 output columns x all 1024 channels; channel reduction via LDS tree.
// Grid: 512 blocks x 16 waves = 8192 waves (32/CU target). No workspace.

constexpr int B    = 8;
constexpr int C    = 1024;
constexpr int T    = 4096;
constexpr int NO   = 21;          // 2*MAX_DISP+1
constexpr int MD   = 10;
constexpr int TILE = 64;          // output cols per block
constexpr int G    = 32;          // channel rows per chunk (= channel groups)
constexpr int NCH  = C / G;       // 32 chunks
constexpr int F2S  = 45;          // f2 row stride in float2 (odd*? -> 2-way-free reads)
constexpr int F1S  = 33;          // f1 row stride in float2
constexpr int DTS  = 129;         // reduce-tree per-g stride in float2 (odd -> spread)

__global__ __launch_bounds__(1024)
void corr_fused(const float* __restrict__ f1g, const float* __restrict__ f2g,
                float* __restrict__ outg)
{
    __shared__ float2 sm[4992];              // 39936 B
    float2* f2b0 = sm;                       // 1440
    float2* f2b1 = sm + G * F2S;             // 1440
    float2* f1b0 = sm + 2 * G * F2S;         // 1056
    float2* f1b1 = f1b0 + G * F1S;           // 1056  (total 4992)

    // XCD swizzle: keep adjacent tiles (halo overlap) on the same XCD's L2
    const int sb   = (int)blockIdx.x;                 // 0..511
    const int flat = (sb & 7) * 64 + (sb >> 3);       // bijective
    const int b    = flat >> 6;
    const int t0   = (flat & 63) * TILE;

    const int tid = (int)threadIdx.x;
    const int g   = tid & 31;                // channel group (row within chunk)
    const int p   = tid >> 5;                // col-pair: cols t0+2p, t0+2p+1

    // --- staging assignments (constant across chunks) ---
    const bool f2act = tid < 704;                     // 32 rows x 22 float4
    const int  r2 = tid / 22;
    const int  v2 = tid - r2 * 22;
    const int  src2 = min(max(t0 - 12 + 4 * v2, 0), T - 4);  // clamped, 16B aligned
    const int  r1 = tid >> 5;
    const int  u1 = tid & 31;

    const float* f2src = f2g + ((size_t)b * C + r2) * T + src2;
    const float* f1src = f1g + ((size_t)b * C + r1) * T + t0 + 2 * u1;

    float accA[NO], accB[NO];
#pragma unroll
    for (int o = 0; o < NO; ++o) { accA[o] = 0.f; accB[o] = 0.f; }
    float  s1a = 0.f, s1b = 0.f, s2a = 0.f, s2b = 0.f;
    float2 s2h; s2h.x = 0.f; s2h.y = 0.f;
    const bool hasH = p < 12;                          // halo ||f2|| columns
    const int  qh   = (p < 6) ? p : p + 32;            // window units 0..5, 38..43

    // prologue: chunk 0 -> regs
    float4 rf2; float2 rf1;
    if (f2act) rf2 = *(const float4*)f2src;
    rf1 = *(const float2*)f1src;

    for (int k = 0; k < NCH; ++k) {
        float2* F2 = (k & 1) ? f2b1 : f2b0;
        float2* F1 = (k & 1) ? f1b1 : f1b0;

        if (f2act) {
            float2 lo; lo.x = rf2.x; lo.y = rf2.y;
            float2 hi; hi.x = rf2.z; hi.y = rf2.w;
            F2[r2 * F2S + 2 * v2]     = lo;
            F2[r2 * F2S + 2 * v2 + 1] = hi;
        }
        F1[r1 * F1S + u1] = rf1;
        __syncthreads();

        // prefetch next chunk into regs (latency hidden under compute)
        if (k + 1 < NCH) {
            const size_t off = (size_t)(k + 1) * G * T;
            if (f2act) rf2 = *(const float4*)(f2src + off);
            rf1 = *(const float2*)(f1src + off);
        }

        const float2 a = F1[g * F1S + p];
        float w[22];
#pragma unroll
        for (int j = 0; j < 11; ++j) {
            float2 v = F2[g * F2S + (p + 1) + j];
            w[2 * j] = v.x; w[2 * j + 1] = v.y;
        }
        if (hasH) {
            float2 h = F2[g * F2S + qh];
            s2h.x += h.x * h.x; s2h.y += h.y * h.y;
        }
        s1a += a.x * a.x;   s1b += a.y * a.y;
        s2a += w[10] * w[10]; s2b += w[11] * w[11];
#pragma unroll
        for (int o = 0; o < NO; ++o) {
            accA[o] += a.x * w[o];
            accB[o] += a.y * w[o + 1];
        }
    }
    __syncthreads();   // main buffers dead; overlay reduction region

    // --- reduction region (overlaps main LDS) ---
    float*  inv = (float*)sm;          // [0,64): inv1 per col; [64,152): inv2 per window float
    float2* s1p = sm + 80;             // 32 x F1S
    float2* s2p = s1p + G * F1S;       // 32 x F2S
    float2* dtp = sm + 80;             // 32 x DTS (reused after norms)

    // norms: write partials
    s1p[g * F1S + p] = make_float2(s1a, s1b);
    s2p[g * F2S + (p + 6)] = make_float2(s2a, s2b);   // own cols = window unit p+6
    if (hasH) s2p[g * F2S + qh] = s2h;
    __syncthreads();

    if (tid < 32) {
        float2 s; s.x = 0.f; s.y = 0.f;
        for (int gg = 0; gg < 32; ++gg) { float2 v = s1p[gg * F1S + tid]; s.x += v.x; s.y += v.y; }
        inv[2 * tid]     = 1.f / fmaxf(sqrtf(s.x), 1e-12f);
        inv[2 * tid + 1] = 1.f / fmaxf(sqrtf(s.y), 1e-12f);
    } else if (tid < 76) {
        const int q = tid - 32;
        float2 s; s.x = 0.f; s.y = 0.f;
        for (int gg = 0; gg < 32; ++gg) { float2 v = s2p[gg * F2S + q]; s.x += v.x; s.y += v.y; }
        inv[64 + 2 * q]     = 1.f / fmaxf(sqrtf(s.x), 1e-12f);
        inv[64 + 2 * q + 1] = 1.f / fmaxf(sqrtf(s.y), 1e-12f);
    }
    __syncthreads();

    // dot reduction, 4 offsets per round (footprint 32*129 float2 = 33 KB)
    for (int r = 0; r < 6; ++r) {
        const int lo = 4 * r;
        const int n  = (NO - lo) < 4 ? (NO - lo) : 4;
        for (int oi = 0; oi < n; ++oi)
            dtp[g * DTS + oi * 32 + p] = make_float2(accA[lo + oi], accB[lo + oi]);
        __syncthreads();
        if (tid < 32 * n) {
            const int q  = tid & 31;
            const int oi = tid >> 5;
            const int o  = lo + oi;
            float2 s; s.x = 0.f; s.y = 0.f;
            for (int gg = 0; gg < 32; ++gg) {
                float2 v = dtp[gg * DTS + oi * 32 + q];
                s.x += v.x; s.y += v.y;
            }
#pragma unroll
            for (int h = 0; h < 2; ++h) {
                const int   t   = t0 + 2 * q + h;
                const float val = h ? s.y : s.x;
                const int   tp  = min(max(t + o - MD, 0), T - 1);
                if (tp - t + MD == o) {      // this task is the clamp-image
                    const float v = val * inv[2 * q + h] * inv[64 + (tp - t0 + 12)];
                    const int olo = (t + o - MD <= 0)     ? 0      : o;
                    const int ohi = (t + o - MD >= T - 1) ? NO - 1 : o;
                    for (int o2 = olo; o2 <= ohi; ++o2)
                        outg[((size_t)b * NO + o2) * T + t] = v;
                }
            }
        }
        __syncthreads();
    }
}

extern "C" void kernel_launch(void* const* d_in, const int* in_sizes, int n_in,
                              void* d_out, int out_size, void* d_ws, size_t ws_size,
                              hipStream_t stream)
{
    const float* f1 = (const float*)d_in[0];
    const float* f2 = (const float*)d_in[1];
    (void)d_ws; (void)ws_size;   // fully fused: no workspace needed
    corr_fused<<<dim3(512), dim3(1024), 0, stream>>>(f1, f2, (float*)d_out);
}

// Round 4
// 45.822 us; speedup vs baseline: 4.1756x; 1.5793x over previous
//
#include <hip/hip_runtime.h>

// TemporalCorrelation as band-GEMM on MFMA — plain-HIP data path only.
// out[b,o,t] = <f1[b,:,t], f2[b,:,clamp(t+o-10)]> / (||f1[:,t]|| ||f2[:,t']||)
// Block: 256 thr (4 waves), tile = 64 t-cols x all 1024 channels.
// Wave w: M-tile [t0+16w,16), N-tiles w,w+1,w+2 of the 96-col f2 window.
// LDS tiles are [16 t][32 c] bf16 (fragment-major): A/B fragments are single
// ds_read_b128 per lane (contiguous k=8*(l>>4)+j). fp32->bf16 transpose done
// at store time via c-pair packed ds_write_b32. Slot-rotate swizzle on both
// sides keeps LDS <=4-way. Norms fp32 from staged loads; edge replicate-pad
// resolved by clamp-redirect in the epilogue.

constexpr int B  = 8;
constexpr int C  = 1024;
constexpr int T  = 4096;
constexpr int NO = 21;
constexpr int MD = 10;

typedef __attribute__((ext_vector_type(8))) short short8;
typedef __attribute__((ext_vector_type(4))) float f32x4;

__device__ inline unsigned bf16rne(float f) {
    unsigned u = __float_as_uint(f);
    return (u + 0x7FFFu + ((u >> 16) & 1u)) >> 16;   // RNE bf16 in low 16
}
__device__ inline unsigned pack2(float lo, float hi) {
    return bf16rne(lo) | (bf16rne(hi) << 16);
}

struct Regs { float4 a0, a1, b0, b0b, b1, b1b; };

__global__ __launch_bounds__(256)
void corr_mfma(const float* __restrict__ f1, const float* __restrict__ f2,
               float* __restrict__ out)
{
    __shared__ short8 stgv[2][640];          // 2 x 5120 hw = 20 KB, 16B aligned
    __shared__ float  sq1buf[64][17];
    __shared__ float  sq2buf[4][96];
    __shared__ float  inv1L[64];
    __shared__ float  inv2L[96];
    __shared__ float  outT[NO][68];

    const int sb   = (int)blockIdx.x;
    const int flat = (sb & 7) * 64 + (sb >> 3);    // XCD swizzle (512%8==0)
    const int b    = flat >> 6;
    const int t0   = (flat & 63) * 64;

    const int tid  = (int)threadIdx.x;
    const int lane = tid & 63;
    const int w    = tid >> 6;                     // wave id = M-tile id

    // ---- staging maps (constant across chunks) ----
    const int u1 = tid & 15;                       // f1 t-run (4 cols)
    const int q1 = tid >> 4;                       // f1 c-pair: rows 2q1,2q1+1
    const int r2 = tid & 15;                       // f2 window run (4 cols)
    const int q2 = tid >> 4;                       // f2 c-pair
    const bool x2 = (r2 < 8);                      // also stages run 16+r2

    const float* f1p = f1 + ((size_t)b * C + 2 * q1) * T + t0 + 4 * u1;
    const float* f2p = f2 + ((size_t)b * C + 2 * q2) * T;
    const int cA = min(max(t0 - 16 + 4 * r2,        0), T - 4);  // clamped src
    const int cB = min(max(t0 - 16 + 4 * (16 + r2), 0), T - 4);

    // store hw offsets: tile=[16t][32c], elem(t,c) at t*32 + slot'*8 + (c&7),
    // slot' = ((c>>3) + (t>>2)) & 3. Writes step +32 hw per t (i=0..3).
    const int f1hw = (u1 >> 2) * 512 + 4 * (u1 & 3) * 32
                   + ((((q1 >> 2) + (u1 & 3)) & 3) << 3) + 2 * (q1 & 3);
    const int f2hwA = 2048 + (r2 >> 2) * 512 + 4 * (r2 & 3) * 32
                    + ((((q2 >> 2) + (r2 & 3)) & 3) << 3) + 2 * (q2 & 3);
    const int f2hwB = f2hwA + 2048;               // run 16+r2: tile +4

    // fragment read offset (within a tile): lane wants t=lane&15, c-slot=lane>>4
    const int ft  = lane & 15;
    const int fhw = ft * 32 + ((((lane >> 4) + (ft >> 2)) & 3) << 3);

    float sq1[4]  = {0.f, 0.f, 0.f, 0.f};
    float sq2a[4] = {0.f, 0.f, 0.f, 0.f};
    float sq2b[4] = {0.f, 0.f, 0.f, 0.f};
    f32x4 acc0 = {0.f,0.f,0.f,0.f}, acc1 = {0.f,0.f,0.f,0.f}, acc2 = {0.f,0.f,0.f,0.f};

    auto load_chunk = [&](int k) {
        Regs r; const size_t o = (size_t)k * 32 * T;
        r.a0  = *(const float4*)(f1p + o);
        r.a1  = *(const float4*)(f1p + o + T);
        r.b0  = *(const float4*)(f2p + o + cA);
        r.b0b = *(const float4*)(f2p + o + cA + T);
        if (x2) {
            r.b1  = *(const float4*)(f2p + o + cB);
            r.b1b = *(const float4*)(f2p + o + cB + T);
        }
        return r;
    };
    auto commit = [&](const Regs& r, int buf) {
        unsigned short* S = (unsigned short*)&stgv[buf][0];
        const float* a0 = (const float*)&r.a0;  const float* a1 = (const float*)&r.a1;
        const float* b0 = (const float*)&r.b0;  const float* b0b = (const float*)&r.b0b;
        const float* b1 = (const float*)&r.b1;  const float* b1b = (const float*)&r.b1b;
#pragma unroll
        for (int i = 0; i < 4; ++i) {
            *(unsigned*)&S[f1hw  + 32 * i] = pack2(a0[i], a1[i]);
            *(unsigned*)&S[f2hwA + 32 * i] = pack2(b0[i], b0b[i]);
            sq1[i]  += a0[i] * a0[i] + a1[i] * a1[i];
            sq2a[i] += b0[i] * b0[i] + b0b[i] * b0b[i];
        }
        if (x2) {
#pragma unroll
            for (int i = 0; i < 4; ++i) {
                *(unsigned*)&S[f2hwB + 32 * i] = pack2(b1[i], b1b[i]);
                sq2b[i] += b1[i] * b1[i] + b1b[i] * b1b[i];
            }
        }
    };
    auto compute = [&](int buf) {
        const unsigned short* S = (const unsigned short*)&stgv[buf][0];
        short8 af  = *(const short8*)&S[w * 512 + fhw];
        short8 bf0 = *(const short8*)&S[2048 + (w + 0) * 512 + fhw];
        short8 bf1 = *(const short8*)&S[2048 + (w + 1) * 512 + fhw];
        short8 bf2 = *(const short8*)&S[2048 + (w + 2) * 512 + fhw];
        acc0 = __builtin_amdgcn_mfma_f32_16x16x32_bf16(af, bf0, acc0, 0, 0, 0);
        acc1 = __builtin_amdgcn_mfma_f32_16x16x32_bf16(af, bf1, acc1, 0, 0, 0);
        acc2 = __builtin_amdgcn_mfma_f32_16x16x32_bf16(af, bf2, acc2, 0, 0, 0);
    };

    // ---- depth-2 pipelined K-loop, double-buffered LDS ----
    Regs RA = load_chunk(0), RB = load_chunk(1);
    for (int k = 0; k < 32; k += 2) {
        commit(RA, 0);
        __syncthreads();
        if (k + 2 < 32) RA = load_chunk(k + 2);
        compute(0);
        commit(RB, 1);
        __syncthreads();
        if (k + 3 < 32) RB = load_chunk(k + 3);
        compute(1);
    }

    // ---- norms ----
#pragma unroll
    for (int e = 0; e < 4; ++e) sq1buf[4 * u1 + e][q1] = sq1[e];
#pragma unroll
    for (int i = 0; i < 4; ++i) {
        sq2a[i] += __shfl_xor(sq2a[i], 16, 64);
        sq2a[i] += __shfl_xor(sq2a[i], 32, 64);
        sq2b[i] += __shfl_xor(sq2b[i], 16, 64);
        sq2b[i] += __shfl_xor(sq2b[i], 32, 64);
    }
    if (lane < 16) {
#pragma unroll
        for (int i = 0; i < 4; ++i) sq2buf[w][4 * lane + i] = sq2a[i];
    }
    if (lane < 8) {
#pragma unroll
        for (int i = 0; i < 4; ++i) sq2buf[w][64 + 4 * lane + i] = sq2b[i];
    }
    __syncthreads();
    if (tid < 64) {
        float s = 0.f;
#pragma unroll
        for (int g = 0; g < 16; ++g) s += sq1buf[tid][g];
        inv1L[tid] = 1.f / fmaxf(sqrtf(s), 1e-12f);
    } else if (tid < 160) {
        const int f = tid - 64;
        float s = sq2buf[0][f] + sq2buf[1][f] + sq2buf[2][f] + sq2buf[3][f];
        inv2L[f] = 1.f / fmaxf(sqrtf(s), 1e-12f);
    }
    __syncthreads();

    // ---- epilogue: band elems -> outT with clamp-redirect, then coalesced ----
    const int m0  = t0 + w * 16;
    const int cr  = lane & 15;            // N-col within tile
    const int rr4 = (lane >> 4) * 4;      // M-row base
#define EPI(nt, A)                                                          \
    {                                                                       \
        const int tp = t0 - 16 + (w + (nt)) * 16 + cr;                      \
        _Pragma("unroll")                                                   \
        for (int r = 0; r < 4; ++r) {                                       \
            const int t = m0 + rr4 + r;                                     \
            const int d = tp - t;                                           \
            if (tp >= 0 && tp < T && d >= -MD && d <= MD) {                 \
                const float val = (A)[r] * inv1L[t - t0] * inv2L[tp - t0 + 16]; \
                const int on  = d + MD;                                     \
                const int olo = (tp == 0)     ? 0      : on;                \
                const int ohi = (tp == T - 1) ? NO - 1 : on;                \
                for (int o = olo; o <= ohi; ++o) outT[o][t - t0] = val;     \
            }                                                               \
        }                                                                   \
    }
    EPI(0, acc0) EPI(1, acc1) EPI(2, acc2)
#undef EPI
    __syncthreads();

    for (int task = tid; task < NO * 16; task += 256) {
        const int o  = task >> 4;
        const int t4 = (task & 15) * 4;
        const float4 v = *(const float4*)&outT[o][t4];
        *(float4*)(out + ((size_t)b * NO + o) * T + t0 + t4) = v;
    }
}

extern "C" void kernel_launch(void* const* d_in, const int* in_sizes, int n_in,
                              void* d_out, int out_size, void* d_ws, size_t ws_size,
                              hipStream_t stream)
{
    const float* f1 = (const float*)d_in[0];
    const float* f2 = (const float*)d_in[1];
    (void)d_ws; (void)ws_size;
    corr_mfma<<<dim3(512), dim3(256), 0, stream>>>(f1, f2, (float*)d_out);
}